// Round 5
// baseline (533.444 us; speedup 1.0000x reference)
//
#include <hip/hip_runtime.h>

#define NLOC  10
#define NGI   13
#define NPAIR 55
#define PNROW 16   // padded row stride for the pn table (scalar-load batching)

typedef float vf4 __attribute__((ext_vector_type(4)));
typedef float vf2 __attribute__((ext_vector_type(2)));

// pn[(i*10+j)*16 + g] = n[i,g]*n[j,g]/dt  (g<13; pad zeroed)
__global__ void prodn_kernel(const float* __restrict__ nmat,
                             const float* __restrict__ dtp,
                             float* __restrict__ pn) {
    int idx = blockIdx.x * blockDim.x + threadIdx.x;
    if (idx >= NLOC * NLOC * PNROW) return;
    int g  = idx % PNROW;
    int ij = idx / PNROW;
    int i  = ij / NLOC, j = ij % NLOC;
    pn[idx] = (g < NGI) ? nmat[i * NGI + g] * nmat[j * NGI + g] / dtp[0] : 0.0f;
}

__device__ __forceinline__ constexpr int pidx(int i, int j) {
    int lo = i < j ? i : j, hi = i < j ? j : i;
    return lo * NLOC - (lo * (lo - 1)) / 2 + (hi - lo);
}

// literal-index component extract — folds at compile time after unroll
__device__ __forceinline__ float cmp4(float4 v, int c) {
    switch (c & 3) {
        case 0:  return v.x;
        case 1:  return v.y;
        case 2:  return v.z;
        default: return v.w;
    }
}

__global__ __launch_bounds__(256) void fem_kernel(
    const float* __restrict__ r0_in,
    const float* __restrict__ c_i,
    const float* __restrict__ c_n,
    const float* __restrict__ kp,
    const float* __restrict__ nx,
    const float* __restrict__ detwei,
    const float* __restrict__ pn,
    float* __restrict__ out,
    int nele)
{
    int e = blockIdx.x * blockDim.x + threadIdx.x;
    if (e >= nele) return;

    const float kk = kp[0];

    float dw[NGI];
    {
        const float* dwp = detwei + (size_t)e * NGI;
        #pragma unroll
        for (int g = 0; g < NGI; ++g) dw[g] = dwp[g];
    }
    float s[NGI];
    #pragma unroll
    for (int g = 0; g < NGI; ++g) s[g] = sqrtf(dw[g]);

    float acc[NPAIR];
    #pragma unroll
    for (int p = 0; p < NPAIR; ++p) acc[p] = 0.0f;

    const float* base = nx + (size_t)e * (2 * NLOC * NGI);  // 1040 B, 16B-aligned

    // ---------------- phase A: dim 0, flat floats [0,130) ----------------
    {
        float4 rv[32];
        #pragma unroll
        for (int q = 0; q < 32; ++q)
            rv[q] = reinterpret_cast<const float4*>(base)[q];      // deep VMEM queue
        float2 t = reinterpret_cast<const float2*>(base)[64];      // floats 128,129

        // in-place scale by s[g], g = flat_idx % 13 (both gram factors carry sqrt(dw))
        #pragma unroll
        for (int q = 0; q < 32; ++q) {
            rv[q].x *= s[(4 * q + 0) % NGI];
            rv[q].y *= s[(4 * q + 1) % NGI];
            rv[q].z *= s[(4 * q + 2) % NGI];
            rv[q].w *= s[(4 * q + 3) % NGI];
        }
        t.x *= s[128 % NGI];  // g=11
        t.y *= s[129 % NGI];  // g=12

        auto G = [&](int idx) -> float {   // idx literal after unroll
            return idx < 128 ? cmp4(rv[idx >> 2], idx)
                             : (idx == 128 ? t.x : t.y);
        };
        #pragma unroll
        for (int i = 0; i < NLOC; ++i)
            #pragma unroll
            for (int j = i; j < NLOC; ++j) {
                float a = acc[pidx(i, j)];
                #pragma unroll
                for (int g = 0; g < NGI; ++g)
                    a = fmaf(G(i * NGI + g), G(j * NGI + g), a);
                acc[pidx(i, j)] = a;
            }
    }
    // ---------------- phase B: dim 1, flat floats [130,260) ----------------
    {
        float2 t = reinterpret_cast<const float2*>(base)[65];      // floats 130,131
        float4 rv[32];
        #pragma unroll
        for (int q = 0; q < 32; ++q)
            rv[q] = reinterpret_cast<const float4*>(base + 132)[q];  // byte 528, 16B-aligned

        t.x *= s[0];
        t.y *= s[1];
        #pragma unroll
        for (int q = 0; q < 32; ++q) {     // local idx = 2+4q+c → g = (2+4q+c) % 13
            rv[q].x *= s[(4 * q + 2) % NGI];
            rv[q].y *= s[(4 * q + 3) % NGI];
            rv[q].z *= s[(4 * q + 4) % NGI];
            rv[q].w *= s[(4 * q + 5) % NGI];
        }
        auto G = [&](int idx) -> float {   // idx in [0,130), local to dim-1 block
            return idx < 2 ? (idx == 0 ? t.x : t.y)
                           : cmp4(rv[(idx - 2) >> 2], idx - 2);
        };
        #pragma unroll
        for (int i = 0; i < NLOC; ++i)
            #pragma unroll
            for (int j = i; j < NLOC; ++j) {
                float a = acc[pidx(i, j)];
                #pragma unroll
                for (int g = 0; g < NGI; ++g)
                    a = fmaf(G(i * NGI + g), G(j * NGI + g), a);
                acc[pidx(i, j)] = a;
            }
    }

    // ---------------- epilogue ----------------
    float ci[NLOC], cn[NLOC], rr[NLOC];
    {
        const float2* p2 = reinterpret_cast<const float2*>(c_i) + (size_t)e * 5;
        #pragma unroll
        for (int q = 0; q < 5; ++q) { float2 v = p2[q]; ci[2*q] = v.x; ci[2*q+1] = v.y; }
    }
    {
        const float2* p2 = reinterpret_cast<const float2*>(c_n) + (size_t)e * 5;
        #pragma unroll
        for (int q = 0; q < 5; ++q) { float2 v = p2[q]; cn[2*q] = v.x; cn[2*q+1] = v.y; }
    }
    {
        const float2* p2 = reinterpret_cast<const float2*>(r0_in) + (size_t)e * 5;
        #pragma unroll
        for (int q = 0; q < 5; ++q) { float2 v = p2[q]; rr[2*q] = v.x; rr[2*q+1] = v.y; }
    }

    float* out_bd = out + (size_t)e * 100;
    float* out_dg = out + (size_t)nele * 100 + (size_t)e * NLOC;
    float* out_r0 = out + (size_t)nele * 110 + (size_t)e * NLOC;

    float dgv[NLOC];
    #pragma unroll
    for (int ip = 0; ip < 5; ++ip) {       // two bd rows per iteration → 80B stores
        float fl[20];
        #pragma unroll
        for (int ii = 0; ii < 2; ++ii) {
            const int i = 2 * ip + ii;
            #pragma unroll
            for (int j = 0; j < NLOC; ++j) {
                // nndt: wave-uniform pn row (scalar loads) dotted with per-element dw
                float nndt = 0.0f;
                #pragma unroll
                for (int g = 0; g < NGI; ++g)
                    nndt = fmaf(pn[(i * NLOC + j) * PNROW + g], dw[g], nndt);
                float A = fmaf(acc[pidx(i, j)], kk, nndt);
                fl[ii * NLOC + j] = A;
                rr[i] = fmaf(nndt, cn[j], rr[i]);
                rr[i] = fmaf(-A, ci[j], rr[i]);
                if (j == i) dgv[i] = A;
            }
        }
        vf4* ob = reinterpret_cast<vf4*>(out_bd + ip * 20);
        #pragma unroll
        for (int q = 0; q < 5; ++q) {
            vf4 v = { fl[4*q], fl[4*q+1], fl[4*q+2], fl[4*q+3] };
            __builtin_nontemporal_store(v, ob + q);
        }
    }
    {
        vf2* od = reinterpret_cast<vf2*>(out_dg);
        #pragma unroll
        for (int q = 0; q < 5; ++q) {
            vf2 v = { dgv[2*q], dgv[2*q+1] };
            __builtin_nontemporal_store(v, od + q);
        }
    }
    {
        vf2* orp = reinterpret_cast<vf2*>(out_r0);
        #pragma unroll
        for (int q = 0; q < 5; ++q) {
            vf2 v = { rr[2*q], rr[2*q+1] };
            __builtin_nontemporal_store(v, orp + q);
        }
    }
}

extern "C" void kernel_launch(void* const* d_in, const int* in_sizes, int n_in,
                              void* d_out, int out_size, void* d_ws, size_t ws_size,
                              hipStream_t stream) {
    const float* r0   = (const float*)d_in[0];
    const float* ci   = (const float*)d_in[1];
    const float* cn   = (const float*)d_in[2];
    const float* k    = (const float*)d_in[3];
    const float* dt   = (const float*)d_in[4];
    const float* nmat = (const float*)d_in[5];
    const float* nx   = (const float*)d_in[6];
    const float* dw   = (const float*)d_in[7];
    int nele = in_sizes[7] / NGI;

    float* pn = (float*)d_ws;   // 100*16 floats = 6.4 KB
    prodn_kernel<<<(NLOC * NLOC * PNROW + 127) / 128, 128, 0, stream>>>(nmat, dt, pn);

    int nb = (nele + 255) / 256;
    fem_kernel<<<nb, 256, 0, stream>>>(r0, ci, cn, k, nx, dw, pn,
                                       (float*)d_out, nele);
}

// Round 6
// 273.844 us; speedup vs baseline: 1.9480x; 1.9480x over previous
//
#include <hip/hip_runtime.h>
#include <stdint.h>

#define NLOC  10
#define NGI   13
#define NPAIR 55
#define EPB   32           // elements per block
#define TPB   64           // threads per block (1 wave)

// granule (16B) region END boundaries within a block's staged data
#define GE_NX 2080         // EPB*65   (nx: 260 floats/elem)
#define GE_DW 2184         // +EPB*13/4 = +104
#define GE_R0 2264         // +EPB*10/4 = +80
#define GE_CI 2344
#define GE_CN 2424
#define NITER 38           // ceil(2424/64)

// LDS word offsets (= granule*4)
#define W_DW  8320
#define W_R0  8736
#define W_CI  9056
#define W_CN  9376
#define W_TOT 9696         // 38784 bytes

typedef float vf2 __attribute__((ext_vector_type(2)));

__device__ __forceinline__ constexpr int pidx(int i, int j) {   // requires i<=j
    return i * NLOC - (i * (i - 1)) / 2 + (j - i);
}

// async global->LDS, 16B per lane; LDS dest = wave-uniform base + lane*16
__device__ __forceinline__ void stage16(const float* gsrc, float* lds) {
    __builtin_amdgcn_global_load_lds(
        (const __attribute__((address_space(1))) void*)gsrc,
        (__attribute__((address_space(3))) void*)lds, 16, 0, 0);
}

__global__ __launch_bounds__(TPB) void fem_kernel(
    const float* __restrict__ r0g,
    const float* __restrict__ cig,
    const float* __restrict__ cng,
    const float* __restrict__ kp,
    const float* __restrict__ dtp,
    const float* __restrict__ nmat,
    const float* __restrict__ nx,
    const float* __restrict__ dwei,
    float* __restrict__ out,
    int nele)
{
    __shared__ float sm[W_TOT];

    const int  t   = threadIdx.x;
    const long e0  = (long)blockIdx.x * EPB;
    const int  rem = min(EPB, nele - (int)e0);

    // ---------------- stage: flat coalesced granule copy ----------------
    const float* nxsrc = nx + (size_t)e0 * 260;
    const int capnx = rem * 260;                      // valid floats in nx region
    #pragma unroll
    for (int k = 0; k < 32; ++k) {                    // G < 2048: pure-nx fast path
        const int G = k * 64 + t;
        if (G * 4 < capnx) stage16(nxsrc + (size_t)G * 4, sm + k * 256);
    }
    for (int k = 32; k < NITER; ++k) {                // mixed-region tail
        const int G = k * 64 + t;
        const float* src; int rel, capf;
        if (G < GE_NX)      { src = nxsrc;                   rel = G;         capf = capnx;    }
        else if (G < GE_DW) { src = dwei + (size_t)e0 * 13;  rel = G - GE_NX; capf = rem * 13; }
        else if (G < GE_R0) { src = r0g  + (size_t)e0 * 10;  rel = G - GE_DW; capf = rem * 10; }
        else if (G < GE_CI) { src = cig  + (size_t)e0 * 10;  rel = G - GE_R0; capf = rem * 10; }
        else                { src = cng  + (size_t)e0 * 10;  rel = G - GE_CI; capf = rem * 10; }
        if (G < GE_CN && rel * 4 < capf)
            stage16(src + (size_t)rel * 4, sm + k * 256);
    }
    __syncthreads();   // drains vmcnt for global_load_lds

    // ---------------- compute: 2 threads per element (one per dim) -------
    const int  eloc = t >> 1;
    const int  d    = t & 1;
    const long e    = e0 + eloc;
    const bool live = eloc < rem;

    const float kk  = kp[0];
    const float idt = 1.0f / dtp[0];

    float dwreg[NGI];
    #pragma unroll
    for (int g = 0; g < NGI; ++g) dwreg[g] = sm[W_DW + eloc * 13 + g];
    float civ[NLOC], dif[NLOC];
    #pragma unroll
    for (int l = 0; l < NLOC; ++l) civ[l] = sm[W_CI + eloc * 10 + l];
    #pragma unroll
    for (int l = 0; l < NLOC; ++l) dif[l] = sm[W_CN + eloc * 10 + l] - civ[l];

    float acc[NPAIR];
    #pragma unroll
    for (int p = 0; p < NPAIR; ++p) acc[p] = 0.0f;
    float r0a[NLOC];
    #pragma unroll
    for (int i = 0; i < NLOC; ++i) r0a[i] = 0.0f;

    // stiffness gram (this thread's dim), k folded per-g; r0 -= k*nxnx*ci factorized
    const int nxb = eloc * 260 + d * 130;
    #pragma unroll
    for (int g = 0; g < NGI; ++g) {
        float col[NLOC];
        #pragma unroll
        for (int l = 0; l < NLOC; ++l) col[l] = sm[nxb + l * 13 + g];
        const float kdw = kk * dwreg[g];
        float u = 0.0f;
        #pragma unroll
        for (int l = 0; l < NLOC; ++l) u = fmaf(col[l], civ[l], u);
        const float ukdw = u * kdw;
        #pragma unroll
        for (int i = 0; i < NLOC; ++i) {
            const float ti = col[i] * kdw;
            #pragma unroll
            for (int j = i; j < NLOC; ++j)
                acc[pidx(i, j)] = fmaf(ti, col[j], acc[pidx(i, j)]);
            r0a[i] = fmaf(-col[i], ukdw, r0a[i]);
        }
    }

    // mass part (weight idt*dw folded), g-parity split across the d-pair;
    // r0 += nndt*(cn-ci) factorized through quadrature
    #pragma unroll
    for (int gg = 0; gg < 7; ++gg) {
        const int graw = 2 * gg + d;
        const int g = graw < 12 ? graw : 12;
        const float w = (graw < NGI) ? idt * dwreg[g] : 0.0f;
        float ncol[NLOC];
        #pragma unroll
        for (int l = 0; l < NLOC; ++l) ncol[l] = nmat[l * NGI + g];
        float wd = 0.0f;
        #pragma unroll
        for (int l = 0; l < NLOC; ++l) wd = fmaf(ncol[l], dif[l], wd);
        #pragma unroll
        for (int i = 0; i < NLOC; ++i) {
            const float ti = ncol[i] * w;
            #pragma unroll
            for (int j = i; j < NLOC; ++j)
                acc[pidx(i, j)] = fmaf(ti, ncol[j], acc[pidx(i, j)]);
            r0a[i] = fmaf(ti, wd, r0a[i]);
        }
    }

    // combine the dim-pair
    #pragma unroll
    for (int p = 0; p < NPAIR; ++p) acc[p] += __shfl_xor(acc[p], 1);
    #pragma unroll
    for (int i = 0; i < NLOC; ++i) r0a[i] += __shfl_xor(r0a[i], 1);

    // ---------------- epilogue: split rows by d ----------------
    if (live) {
        float* obd = out + (size_t)e * 100;
        float* odg = out + (size_t)nele * 100 + (size_t)e * 10;
        float* oro = out + (size_t)nele * 110 + (size_t)e * 10;
        #pragma unroll
        for (int ii = 0; ii < 5; ++ii) {
            const int i = d * 5 + ii;
            float row[NLOC];
            #pragma unroll
            for (int j = 0; j < NLOC; ++j) {
                const int lo = i < j ? i : j, hi = i < j ? j : i;
                row[j] = acc[pidx(lo, hi)];
            }
            #pragma unroll
            for (int q = 0; q < 5; ++q) {
                vf2 v = { row[2 * q], row[2 * q + 1] };
                *reinterpret_cast<vf2*>(obd + i * 10 + 2 * q) = v;
            }
            odg[i] = row[i];
            oro[i] = sm[W_R0 + eloc * 10 + i] + r0a[i];
        }
    }
}

extern "C" void kernel_launch(void* const* d_in, const int* in_sizes, int n_in,
                              void* d_out, int out_size, void* d_ws, size_t ws_size,
                              hipStream_t stream) {
    const float* r0   = (const float*)d_in[0];
    const float* ci   = (const float*)d_in[1];
    const float* cn   = (const float*)d_in[2];
    const float* k    = (const float*)d_in[3];
    const float* dt   = (const float*)d_in[4];
    const float* nmat = (const float*)d_in[5];
    const float* nx   = (const float*)d_in[6];
    const float* dw   = (const float*)d_in[7];
    const int nele = in_sizes[7] / NGI;

    const int nb = (nele + EPB - 1) / EPB;
    fem_kernel<<<nb, TPB, 0, stream>>>(r0, ci, cn, k, dt, nmat, nx, dw,
                                       (float*)d_out, nele);
}

// Round 7
// 209.304 us; speedup vs baseline: 2.5487x; 1.3084x over previous
//
#include <hip/hip_runtime.h>

#define NLOC  10
#define NGI   13
#define NPAIR 55
#define EPB   64           // elements per block
#define TPB   256          // 4 waves; 4 threads per element

// LDS float offsets
#define W_NX   0           // EPB*260 = 16640 floats
#define W_DW   16640       // EPB*13  = 832 floats
#define W_N    17472       // 130 floats (shape-function table)
#define W_TOT  17604       // 70416 B -> 2 blocks/CU

#define NX_GRAN  4160      // 16B granules in nx region (16640/4)
#define TOT_GRAN 4368      // + 208 dw granules

typedef float vf2 __attribute__((ext_vector_type(2)));

__device__ __forceinline__ constexpr int pidx(int i, int j) {   // requires i<=j
    return i * NLOC - (i * (i - 1)) / 2 + (j - i);
}

// async global->LDS, 16B/lane; lds base wave-uniform, HW adds lane*16
__device__ __forceinline__ void stage16(const float* gsrc, float* lds) {
    __builtin_amdgcn_global_load_lds(
        (const __attribute__((address_space(1))) void*)gsrc,
        (__attribute__((address_space(3))) void*)lds, 16, 0, 0);
}

__global__ __launch_bounds__(TPB) void fem_kernel(
    const float* __restrict__ r0g,
    const float* __restrict__ cig,
    const float* __restrict__ cng,
    const float* __restrict__ kp,
    const float* __restrict__ dtp,
    const float* __restrict__ nmat,
    const float* __restrict__ nx,
    const float* __restrict__ dwei,
    float* __restrict__ out,
    int nele)
{
    __shared__ float sm[W_TOT];

    const int  t   = threadIdx.x;
    const long e0  = (long)blockIdx.x * EPB;
    const int  rem = min(EPB, nele - (int)e0);

    // ---------------- stage: flat coalesced granule copy (nx, dw) --------
    const float* nxsrc = nx   + (size_t)e0 * 260;
    const float* dwsrc = dwei + (size_t)e0 * 13;
    const int capnx = rem * 260;     // valid floats (both %4 == 0)
    const int capdw = rem * 13;
    float* ldsb = sm + (t >> 6) * 256;   // per-wave uniform base (floats)
    #pragma unroll
    for (int k = 0; k < 18; ++k) {
        const int G = k * 256 + t;       // granule index; LDS float off = G*4
        if (G < NX_GRAN) {
            if (G * 4 < capnx) stage16(nxsrc + (size_t)G * 4, ldsb + k * 1024);
        } else if (G < TOT_GRAN) {
            const int rel = G - NX_GRAN;
            if (rel * 4 < capdw) stage16(dwsrc + (size_t)rel * 4, ldsb + k * 1024);
        }
    }
    if (t < 130) sm[W_N + t] = nmat[t];  // 520B coalesced, reused all block
    __syncthreads();                     // drains vmcnt per wave

    // ---------------- compute: 4 threads per element ---------------------
    const int  eloc = t >> 2;
    const int  d    = (t >> 1) & 1;      // spatial dim (stiffness)
    const int  h    = t & 1;             // g-parity (stiffness)
    const int  q    = t & 3;             // g-stride-4 slot (mass, epilogue)
    const long e    = e0 + eloc;
    const bool live = eloc < rem;
    const long ee   = live ? e : (long)(nele - 1);   // clamp for global reads

    const float kk  = kp[0];
    const float idt = 1.0f / dtp[0];

    const float* smnx = sm + eloc * 260 + d * 130;
    const float* smdw = sm + W_DW + eloc * 13;
    const float* smn  = sm + W_N;

    float civ[NLOC], dif[NLOC];
    {
        const vf2* ci2 = reinterpret_cast<const vf2*>(cig + (size_t)ee * 10);
        const vf2* cn2 = reinterpret_cast<const vf2*>(cng + (size_t)ee * 10);
        #pragma unroll
        for (int u2 = 0; u2 < 5; ++u2) {
            vf2 a = ci2[u2], b = cn2[u2];
            civ[2*u2]   = a.x; civ[2*u2+1] = a.y;
            dif[2*u2]   = b.x - a.x; dif[2*u2+1] = b.y - a.y;
        }
    }

    float acc[NPAIR];
    #pragma unroll
    for (int p = 0; p < NPAIR; ++p) acc[p] = 0.0f;
    float r0a[NLOC];
    #pragma unroll
    for (int i = 0; i < NLOC; ++i) r0a[i] = 0.0f;

    // stiffness: this thread's dim d, g = 2*it + h (7 iters, last guarded)
    #pragma unroll
    for (int it = 0; it < 7; ++it) {
        const int   graw = 2 * it + h;
        const int   g    = graw < NGI ? graw : NGI - 1;
        const float wv   = graw < NGI ? kk * smdw[g] : 0.0f;
        float col[NLOC];
        #pragma unroll
        for (int l = 0; l < NLOC; ++l) col[l] = smnx[l * 13 + g];
        float u = 0.0f;
        #pragma unroll
        for (int l = 0; l < NLOC; ++l) u = fmaf(col[l], civ[l], u);
        const float uw = u * wv;
        #pragma unroll
        for (int i = 0; i < NLOC; ++i) {
            const float ti = col[i] * wv;
            #pragma unroll
            for (int j = i; j < NLOC; ++j)
                acc[pidx(i, j)] = fmaf(ti, col[j], acc[pidx(i, j)]);
            r0a[i] = fmaf(-col[i], uw, r0a[i]);
        }
    }

    // mass: g = q + 4*it (4 iters, guarded); weight idt*dw; r0 += nn/dt*(cn-ci)
    #pragma unroll
    for (int it = 0; it < 4; ++it) {
        const int   graw = q + 4 * it;
        const int   g    = graw < NGI ? graw : NGI - 1;
        const float wv   = graw < NGI ? idt * smdw[g] : 0.0f;
        float ncol[NLOC];
        #pragma unroll
        for (int l = 0; l < NLOC; ++l) ncol[l] = smn[l * 13 + g];
        float wd = 0.0f;
        #pragma unroll
        for (int l = 0; l < NLOC; ++l) wd = fmaf(ncol[l], dif[l], wd);
        #pragma unroll
        for (int i = 0; i < NLOC; ++i) {
            const float ti = ncol[i] * wv;
            #pragma unroll
            for (int j = i; j < NLOC; ++j)
                acc[pidx(i, j)] = fmaf(ti, ncol[j], acc[pidx(i, j)]);
            r0a[i] = fmaf(ti, wd, r0a[i]);
        }
    }

    // combine the 4 partial sums (quad butterfly)
    #pragma unroll
    for (int p = 0; p < NPAIR; ++p) {
        acc[p] += __shfl_xor(acc[p], 1);
        acc[p] += __shfl_xor(acc[p], 2);
    }
    #pragma unroll
    for (int i = 0; i < NLOC; ++i) {
        r0a[i] += __shfl_xor(r0a[i], 1);
        r0a[i] += __shfl_xor(r0a[i], 2);
    }

    // ---------------- epilogue: rows split by (i&3)==q, literal indices --
    if (live) {
        float* obd = out + (size_t)e * 100;
        float* odg = out + (size_t)nele * 100 + (size_t)e * 10;
        float* oro = out + (size_t)nele * 110 + (size_t)e * 10;
        const float* r0s = r0g + (size_t)e * 10;
        #pragma unroll
        for (int i = 0; i < NLOC; ++i) {
            if ((i & 3) == q) {
                float row[NLOC];
                #pragma unroll
                for (int j = 0; j < NLOC; ++j) {
                    const int lo = i < j ? i : j, hi = i < j ? j : i;
                    row[j] = acc[pidx(lo, hi)];
                }
                #pragma unroll
                for (int u2 = 0; u2 < 5; ++u2) {
                    vf2 v = { row[2*u2], row[2*u2+1] };
                    *reinterpret_cast<vf2*>(obd + i * 10 + 2 * u2) = v;
                }
                odg[i] = row[i];
                oro[i] = r0s[i] + r0a[i];
            }
        }
    }
}

extern "C" void kernel_launch(void* const* d_in, const int* in_sizes, int n_in,
                              void* d_out, int out_size, void* d_ws, size_t ws_size,
                              hipStream_t stream) {
    const float* r0   = (const float*)d_in[0];
    const float* ci   = (const float*)d_in[1];
    const float* cn   = (const float*)d_in[2];
    const float* k    = (const float*)d_in[3];
    const float* dt   = (const float*)d_in[4];
    const float* nmat = (const float*)d_in[5];
    const float* nx   = (const float*)d_in[6];
    const float* dw   = (const float*)d_in[7];
    const int nele = in_sizes[7] / NGI;

    const int nb = (nele + EPB - 1) / EPB;
    fem_kernel<<<nb, TPB, 0, stream>>>(r0, ci, cn, k, dt, nmat, nx, dw,
                                       (float*)d_out, nele);
}